// Round 14
// baseline (877.284 us; speedup 1.0000x reference)
//
#include <hip/hip_runtime.h>
#include <hip/hip_bf16.h>

typedef __attribute__((ext_vector_type(8))) short bf16x8;
typedef __attribute__((ext_vector_type(4))) float f32x4;

static __device__ __forceinline__ unsigned short f2bf(float x) {
    __hip_bfloat16 h = __float2bfloat16(x);
    return *(unsigned short*)&h;
}
static __device__ __forceinline__ float bflo(unsigned int w) { return __uint_as_float(w << 16); }
static __device__ __forceinline__ float bfhi(unsigned int w) { return __uint_as_float(w & 0xffff0000u); }
static __device__ __forceinline__ float bf1(unsigned short u) { return __uint_as_float(((unsigned int)u) << 16); }

// async global->LDS DMA, 16B per lane, dest = wave-uniform base + lane*16
typedef __attribute__((address_space(1))) const void gvoid;
typedef __attribute__((address_space(3))) void lvoid;
static __device__ __forceinline__ void gl_lds16(const void* g, void* l) {
    __builtin_amdgcn_global_load_lds((gvoid*)g, (lvoid*)l, 16, 0, 0);
}

#define PART_FLOATS 4718592   // 512*9216

// ---------------- conv1 via bf16 MFMA implicit GEMM -------------------------------------
// R24: conv1 was the last matmul-shaped fp32-VALU kernel (floor 54us @ 157 TF; no fp32
// MFMA on CDNA4). Now implicit GEMM: M=400 pix/image (pad 448), N=64 couts/block
// (grid 512 x 4), K=81 (pad 96 = 3 steps of 32). Per block: image -> bf16 LDS; Bt[3]
// [64][32] built once; per K-step build im2col A[448][32] and run MFMA (7 M-tiles x
// 4 N-tiles per wave). Swizzle ch=(row>>1)&3 on 16B chunks -> exactly 2 lanes/bank
// group (free, m136). Fragment/operand/epilogue conventions copied from verified
// conv2_k ([outdim][K] row-major both operands; C/D col=lane&15, row=quad*4+rg).
// h1n layout unchanged: [b*400 + oy*20+ox][256] bf16.
__global__ __launch_bounds__(256) void conv1_k(const float* __restrict__ in,
                                               const float* __restrict__ w,
                                               const float* __restrict__ bias,
                                               unsigned short* __restrict__ h1n) {
    int b = blockIdx.x;
    int c0 = blockIdx.y * 64;
    int tid = threadIdx.x;
    __shared__ unsigned short imgbf[784];
    __shared__ unsigned short Al[448 * 32];      // 28 KB, swizzled
    __shared__ unsigned short Btl[3][64 * 32];   // 12 KB, swizzled

    // stage image -> bf16 (196 float4)
    if (tid < 196) {
        float4 v = *(const float4*)&in[b * 784 + tid * 4];
        imgbf[tid * 4 + 0] = f2bf(v.x);
        imgbf[tid * 4 + 1] = f2bf(v.y);
        imgbf[tid * 4 + 2] = f2bf(v.z);
        imgbf[tid * 4 + 3] = f2bf(v.w);
    }
    // build all 3 Bt K-step tiles (w[cout][k], k pad 96)
    for (int idx = tid; idx < 6144; idx += 256) {
        int ksb = idx >> 11;
        int r = idx & 2047;
        int c = r >> 5, kid = r & 31;
        int k = ksb * 32 + kid;
        unsigned short v = (k < 81) ? f2bf(w[(size_t)(c0 + c) * 81 + k]) : (unsigned short)0;
        Btl[ksb][c * 32 + 8 * ((kid >> 3) ^ ((c >> 1) & 3)) + (kid & 7)] = v;
    }

    int wv = tid >> 6, lane = tid & 63;
    int lr = lane & 15, quad = lane >> 4;
    int wrow = wv * 112;

    f32x4 acc[7][4];
#pragma unroll
    for (int mi = 0; mi < 7; mi++)
#pragma unroll
        for (int ni = 0; ni < 4; ni++) acc[mi][ni] = (f32x4){0.f, 0.f, 0.f, 0.f};

    __syncthreads();

#pragma unroll 1
    for (int ks = 0; ks < 3; ks++) {
        // im2col build: A[row=(oy*20+ox)][kid], k = ks*32+kid = ky*9+kx
        for (int idx = tid; idx < 14336; idx += 256) {
            int row = idx >> 5, kid = idx & 31;
            int k = ks * 32 + kid;
            unsigned short v = 0;
            if (row < 400 && k < 81) {
                int oy = row / 20, ox = row - oy * 20;
                int ky = k / 9, kx = k - ky * 9;
                v = imgbf[(oy + ky) * 28 + ox + kx];
            }
            Al[row * 32 + 8 * ((kid >> 3) ^ ((row >> 1) & 3)) + (kid & 7)] = v;
        }
        __syncthreads();
        bf16x8 bf[4];
#pragma unroll
        for (int ni = 0; ni < 4; ni++) {
            int c = ni * 16 + lr;
            bf[ni] = *(const bf16x8*)&Btl[ks][c * 32 + 8 * (quad ^ ((c >> 1) & 3))];
        }
#pragma unroll
        for (int mi = 0; mi < 7; mi++) {
            int row = wrow + mi * 16 + lr;
            bf16x8 av = *(const bf16x8*)&Al[row * 32 + 8 * (quad ^ ((row >> 1) & 3))];
#pragma unroll
            for (int ni = 0; ni < 4; ni++)
                acc[mi][ni] = __builtin_amdgcn_mfma_f32_16x16x32_bf16(
                    av, bf[ni], acc[mi][ni], 0, 0, 0);
        }
        __syncthreads();   // before next ks overwrites Al
    }

    // epilogue: bias + ReLU + bf16 store; skip pad rows
#pragma unroll
    for (int ni = 0; ni < 4; ni++) {
        int c = c0 + ni * 16 + lr;
        float bv = bias[c];
#pragma unroll
        for (int mi = 0; mi < 7; mi++) {
#pragma unroll
            for (int rg = 0; rg < 4; rg++) {
                int p = wrow + mi * 16 + quad * 4 + rg;
                if (p < 400)
                    h1n[((size_t)b * 400 + p) * 256 + c] =
                        f2bf(fmaxf(acc[mi][ni][rg] + bv, 0.f));
            }
        }
    }
}

// ---------------- W2 transpose (84 kk planes; 81..83 zeroed for uniform split-K 4) -------
// R23: one coalesced float4 pass -> bf16 LDS [cin][84] -> vectorized plane writes.
__global__ __launch_bounds__(256) void wt2_k(const float* __restrict__ w2,
                                             unsigned short* __restrict__ Wt2) {
    int cout = blockIdx.x;
    int tid = threadIdx.x;
    __shared__ unsigned short lw[256 * 84];   // 43 KB
    lw[tid * 84 + 81] = 0; lw[tid * 84 + 82] = 0; lw[tid * 84 + 83] = 0;
    const float4* src = (const float4*)(w2 + (size_t)cout * 20736);
    for (int t = tid; t < 5184; t += 256) {
        float4 v = src[t];
        int flat = t * 4;
#pragma unroll
        for (int e = 0; e < 4; e++) {
            int f = flat + e;
            int cin = f / 81, kk = f - cin * 81;
            float x = (e == 0) ? v.x : (e == 1) ? v.y : (e == 2) ? v.z : v.w;
            lw[cin * 84 + kk] = f2bf(x);
        }
    }
    __syncthreads();
    int kko = tid >> 7, c2 = (tid & 127) * 2;
    for (int base = 0; base < 84; base += 2) {
        int kk = base + kko;
        unsigned int val = (unsigned int)lw[c2 * 84 + kk]
                         | ((unsigned int)lw[(c2 + 1) * 84 + kk] << 16);
        *(unsigned int*)&Wt2[(size_t)kk * 65536 + cout * 256 + c2] = val;
    }
}

// ---------------- capW f32 -> bf16 (same flat layout i*1280 + j*128 + p*16 + q) ----------
__global__ __launch_bounds__(256) void wcap_k(const float* __restrict__ W,
                                              unsigned short* __restrict__ Wb) {
    int idx4 = blockIdx.x * 256 + threadIdx.x;   // 368,640 total (1,474,560 / 4)
    float4 v = *(const float4*)&W[(size_t)idx4 * 4];
    unsigned int lo = (unsigned int)f2bf(v.x) | ((unsigned int)f2bf(v.y) << 16);
    unsigned int hi = (unsigned int)f2bf(v.z) | ((unsigned int)f2bf(v.w) << 16);
    uint2 pk; pk.x = lo; pk.y = hi;
    *(uint2*)&Wb[(size_t)idx4 * 4] = pk;
}

// ---------------- conv2 implicit GEMM, bf16 MFMA, 128x128, split-K 4 ---------------------
// R12 (verified best, ~278-294us, SESSION CEILING for this structure): 2-phase double-
// buffered global_load_lds prefetch; one barrier per round; XOR swizzle via pre-swizzled
// SOURCE (rule 21). 64 KB LDS -> 2 blocks/CU.
// Failed alternatives: R16 direct-B regs (540us); R17 BK=32 (294); R18 counted-vmcnt on
// 2-phase (333); R21 XCD decode (299, FETCH 2.4x -> latency-bound proof); R22 BN=256
// 3-ring (360, 1 blk/CU killed TLP).
__global__ __launch_bounds__(256) void conv2_k(const unsigned short* __restrict__ h1n,
                                               const unsigned short* __restrict__ Wt2,
                                               const float* __restrict__ bias,
                                               float* __restrict__ u,
                                               float* __restrict__ part1,
                                               float* __restrict__ part23) {
    __shared__ unsigned short sA[2][128 * 64];   // 32 KB, XOR-swizzled, double-buffered
    __shared__ unsigned short sB[2][128 * 64];   // 32 KB, XOR-swizzled, double-buffered
    int tid = threadIdx.x;
    int m0 = blockIdx.x * 128;
    int n0 = blockIdx.y * 128;
    int slice = blockIdx.z;
    int ks = slice * 21;

    int wv = tid >> 6, lane = tid & 63;
    int wm = wv >> 1, wn = wv & 1;
    int lr = lane & 15, quad = lane >> 4;

    // staging geometry (per wave): 4 instrs for A + 4 for B, 8 rows per instr
    int lrow = lane >> 3, lslot = lane & 7;
    int kcoff = (lslot ^ lrow) * 8;           // pre-swizzled chunk offset (shorts)
    int aG[4], bG[4];
#pragma unroll
    for (int t = 0; t < 4; t++) {
        int r = wv * 32 + t * 8 + lrow;       // sA/sB row this lane feeds in instr t
        int R = m0 + r;
        int b = R / 36, m = R % 36;
        int oy = m / 6, ox = m % 6;
        aG[t] = b * 102400 + oy * 10240 + ox * 512 + kcoff;
        bG[t] = (n0 + r) * 256 + kcoff;
    }

    f32x4 acc[4][4];
#pragma unroll
    for (int i = 0; i < 4; i++)
#pragma unroll
        for (int j = 0; j < 4; j++) acc[i][j] = (f32x4){0.f, 0.f, 0.f, 0.f};

    auto stage = [&](int buf, int rr) {
        int kk = ks + (rr >> 2), cr = rr & 3;      // wave-uniform -> SALU
        int ky = kk / 9, kx = kk % 9;
        int aoff = ky * 5120 + kx * 256 + cr * 64;
        int boff = kk * 65536 + cr * 64;
        unsigned short* dA = &sA[buf][wv * 2048];
        unsigned short* dB = &sB[buf][wv * 2048];
#pragma unroll
        for (int t = 0; t < 4; t++)
            gl_lds16(h1n + aG[t] + aoff, dA + t * 512);
#pragma unroll
        for (int t = 0; t < 4; t++)
            gl_lds16(Wt2 + bG[t] + boff, dB + t * 512);
    };

    // prologue: fill buf0, drain, barrier
    stage(0, 0);
    __syncthreads();

    int cur = 0;
#pragma unroll 1
    for (int rr = 0; rr < 84; rr++) {
        if (rr < 83) stage(cur ^ 1, rr + 1);   // prefetch next round (stays in flight)
        const unsigned short* pA = &sA[cur][0];
        const unsigned short* pB = &sB[cur][0];
#pragma unroll
        for (int s = 0; s < 2; s++) {
            bf16x8 af[4], bf[4];
#pragma unroll
            for (int i = 0; i < 4; i++) {
                int arow = wm * 64 + i * 16 + lr;
                af[i] = *(bf16x8*)&pA[arow * 64 + 8 * ((s * 4 + quad) ^ (lr & 7))];
            }
#pragma unroll
            for (int j = 0; j < 4; j++) {
                int brow = wn * 64 + j * 16 + lr;
                bf[j] = *(bf16x8*)&pB[brow * 64 + 8 * ((s * 4 + quad) ^ (lr & 7))];
            }
#pragma unroll
            for (int i = 0; i < 4; i++)
#pragma unroll
                for (int j = 0; j < 4; j++)
                    acc[i][j] = __builtin_amdgcn_mfma_f32_16x16x32_bf16(
                        af[i], bf[j], acc[i][j], 0, 0, 0);
        }
        __syncthreads();   // drains prefetch vmcnt(0); it had the whole compute to land
        cur ^= 1;
    }

    // epilogue: C/D layout col=lane&15, row=quad*4+reg
    float* dst = (slice == 0) ? u : ((slice == 1) ? part1 : part23 + (size_t)(slice - 2) * PART_FLOATS);
#pragma unroll
    for (int j = 0; j < 4; j++) {
        int col = n0 + wn * 64 + j * 16 + lr;
        float bv = (slice == 0) ? bias[col] : 0.f;
#pragma unroll
        for (int i = 0; i < 4; i++) {
#pragma unroll
            for (int rg = 0; rg < 4; rg++) {
                int RR = m0 + wm * 64 + i * 16 + quad * 4 + rg;
                int bb = RR / 36, mm = RR % 36;
                int oyy = mm / 6, oxx = mm % 6;
                dst[bb * 9216 + oxx * 1536 + oyy * 256 + col] = acc[i][j][rg] + bv;
            }
        }
    }
}

// ---------------- u_hat: (u+p1+p2+p3)[b,i,p] x Wb[i,j,p,q] -> uhat bf16 [b][j][i*16+q] --
// R20 (verified): add-fold (190 MB add pass gone) + bf16 W (wl 16.6 KB) + 8 samples/
// block + float4 x 4-stream staging. LDS 18.4+16.6 = 35 KB -> 4 blocks/CU.
__global__ __launch_bounds__(256) void uhat_k(const float* __restrict__ u,
                                              const float* __restrict__ p1,
                                              const float* __restrict__ p23,
                                              const unsigned short* __restrict__ Wb,
                                              unsigned short* __restrict__ uhat) {
    int i0 = blockIdx.x * 64;
    int b0 = blockIdx.y * 8;      // LOCAL sample index within this chunk
    __shared__ float ul[8 * 576];           // [bb][il*9+p], 18.4 KB
    __shared__ unsigned short wl[64 * 130]; // 16.6 KB
    int tid = threadIdx.x;

    // fold-staging: 1024 float4-groups (8 bb x 128), 4 iterations/thread
    for (int t = tid; t < 1024; t += 256) {
        int bb = t >> 7, rq = t & 127;
        int r = rq * 4;
        size_t gidx = (size_t)(b0 + bb) * 9216 + i0 * 8 + r;
        float4 a = *(const float4*)&u[gidx];
        float4 x = *(const float4*)&p1[gidx];
        float4 y = *(const float4*)&p23[gidx];
        float4 z = *(const float4*)&p23[PART_FLOATS + gidx];
        float* d = &ul[bb * 576 + (r >> 3) * 9 + (r & 7)];
        d[0] = a.x + x.x + y.x + z.x;
        d[1] = a.y + x.y + y.y + z.y;
        d[2] = a.z + x.z + y.z + z.z;
        d[3] = a.w + x.w + y.w + z.w;
    }

    int il = tid & 63, g = tid >> 6;
    for (int j = 0; j < 10; j++) {
        __syncthreads();
        for (int t = tid; t < 4096; t += 256) {
            int li = t >> 6, cp = t & 63;   // 64 uint (2 bf16) per 128-col row
            *(unsigned int*)&wl[li * 130 + cp * 2] =
                *(const unsigned int*)&Wb[(size_t)(i0 + li) * 1280 + j * 128 + cp * 2];
        }
        __syncthreads();
#pragma unroll 1
        for (int bb = 0; bb < 8; bb++) {
            float ur[8];
#pragma unroll
            for (int p = 0; p < 8; p++) ur[p] = ul[bb * 576 + il * 9 + p];
            float a[4];
#pragma unroll
            for (int k = 0; k < 4; k++) {
                int q = g * 4 + k;
                float s = 0.f;
#pragma unroll
                for (int p = 0; p < 8; p++) s += ur[p] * bf1(wl[il * 130 + p * 16 + q]);
                a[k] = s;
            }
            unsigned int lo = (unsigned int)f2bf(a[0]) | ((unsigned int)f2bf(a[1]) << 16);
            unsigned int hi = (unsigned int)f2bf(a[2]) | ((unsigned int)f2bf(a[3]) << 16);
            uint2 pk; pk.x = lo; pk.y = hi;
            *(uint2*)&uhat[((size_t)(b0 + bb) * 10 + j) * 18432 + (size_t)(i0 + il) * 16 + g * 4] = pk;
        }
    }
}

// ---------------- fused dynamic routing: one block per batch sample ----------------------
// R13 (verified): b_ij in LDS, s/v in LDS, zero global atomics, no inter-kernel drains.
// uhat[b] (360 KB, L2/L3-resident) streamed 3x. R14: [b][j][i16q] layout -> 512 B
// contiguous per wave per j.
__global__ __launch_bounds__(256) void route_k(const unsigned short* __restrict__ uhat,
                                               float* __restrict__ out) {
    int b = blockIdx.x;
    int tid = threadIdx.x;
    int w = tid >> 6, lane = tid & 63;
    int ig = lane >> 2, qh = lane & 3;
    __shared__ float b_sh[1152 * 10];   // 46 KB
    __shared__ float s_red[4 * 160];
    __shared__ float v_sh[160];
    __shared__ float sc_sh[10];
    const unsigned short* ub = uhat + (size_t)b * 184320;

    float v_ln[10][4];   // this lane's v[j*16 + qh*4 + k]

    // reduce sp -> s -> squash -> v_sh -> v_ln  (shared tail for every pass)
    auto finish = [&](float sp[10][4]) {
#pragma unroll
        for (int j = 0; j < 10; j++)
#pragma unroll
            for (int k = 0; k < 4; k++) {
                float t = sp[j][k];
                t += __shfl_xor(t, 4);
                t += __shfl_xor(t, 8);
                t += __shfl_xor(t, 16);
                t += __shfl_xor(t, 32);
                sp[j][k] = t;
            }
        if (ig == 0) {   // lanes 0..3 of each wave hold the wave totals
#pragma unroll
            for (int j = 0; j < 10; j++) {
                f32x4 v4 = {sp[j][0], sp[j][1], sp[j][2], sp[j][3]};
                *(f32x4*)&s_red[w * 160 + j * 16 + qh * 4] = v4;
            }
        }
        __syncthreads();
        if (tid < 160) {
            float s = s_red[tid] + s_red[160 + tid] + s_red[320 + tid] + s_red[480 + tid];
            s_red[tid] = s;
        }
        __syncthreads();
        if (tid < 10) {
            float sq = 0.f;
#pragma unroll
            for (int q = 0; q < 16; q++) { float x = s_red[tid * 16 + q]; sq += x * x; }
            float norm = sqrtf(sq + 1e-8f);
            sc_sh[tid] = (sq / (1.0f + sq)) / norm;
        }
        __syncthreads();
        if (tid < 160) v_sh[tid] = s_red[tid] * sc_sh[tid >> 4];
        __syncthreads();
#pragma unroll
        for (int j = 0; j < 10; j++) {
            f32x4 v4 = *(const f32x4*)&v_sh[j * 16 + qh * 4];
            v_ln[j][0] = v4[0]; v_ln[j][1] = v4[1]; v_ln[j][2] = v4[2]; v_ln[j][3] = v4[3];
        }
        __syncthreads();
    };

    // ---- pass 1: c = 0.1 uniform ----
    {
        float sp[10][4];
#pragma unroll
        for (int j = 0; j < 10; j++)
#pragma unroll
            for (int k = 0; k < 4; k++) sp[j][k] = 0.f;
#pragma unroll 2
        for (int r = 0; r < 18; r++) {
            int i = r * 64 + w * 16 + ig;
            const unsigned short* up = ub + (size_t)i * 16 + qh * 4;
            uint2 uh[10];
#pragma unroll
            for (int j = 0; j < 10; j++) uh[j] = *(const uint2*)(up + (size_t)j * 18432);
#pragma unroll
            for (int j = 0; j < 10; j++) {
                sp[j][0] += 0.1f * bflo(uh[j].x);
                sp[j][1] += 0.1f * bfhi(uh[j].x);
                sp[j][2] += 0.1f * bflo(uh[j].y);
                sp[j][3] += 0.1f * bfhi(uh[j].y);
            }
        }
        finish(sp);
    }

    // ---- passes 2,3: delta = uhat.v, b update, softmax, s-accumulate ----
#pragma unroll 1
    for (int pass = 0; pass < 2; pass++) {
        bool first = (pass == 0);    // pass2: b_prev = 0, write b_sh; pass3: read b_sh
        float sp[10][4];
#pragma unroll
        for (int j = 0; j < 10; j++)
#pragma unroll
            for (int k = 0; k < 4; k++) sp[j][k] = 0.f;
#pragma unroll 2
        for (int r = 0; r < 18; r++) {
            int i = r * 64 + w * 16 + ig;
            const unsigned short* up = ub + (size_t)i * 16 + qh * 4;
            uint2 uh[10];
#pragma unroll
            for (int j = 0; j < 10; j++) uh[j] = *(const uint2*)(up + (size_t)j * 18432);
            float d[10];
#pragma unroll
            for (int j = 0; j < 10; j++) {
                d[j] = bflo(uh[j].x) * v_ln[j][0] + bfhi(uh[j].x) * v_ln[j][1]
                     + bflo(uh[j].y) * v_ln[j][2] + bfhi(uh[j].y) * v_ln[j][3];
            }
#pragma unroll
            for (int j = 0; j < 10; j++) {
                d[j] += __shfl_xor(d[j], 1);
                d[j] += __shfl_xor(d[j], 2);
            }
            float bn[10];
            if (first) {
#pragma unroll
                for (int j = 0; j < 10; j++) bn[j] = d[j];
#pragma unroll
                for (int j = 0; j < 10; j++)
                    if (qh == (j & 3)) b_sh[i * 10 + j] = bn[j];
            } else {
#pragma unroll
                for (int j = 0; j < 10; j++) bn[j] = b_sh[i * 10 + j] + d[j];
            }
            float m = bn[0];
#pragma unroll
            for (int j = 1; j < 10; j++) m = fmaxf(m, bn[j]);
            float e[10], sum = 0.f;
#pragma unroll
            for (int j = 0; j < 10; j++) { e[j] = __expf(bn[j] - m); sum += e[j]; }
            float inv = 1.f / sum;
#pragma unroll
            for (int j = 0; j < 10; j++) {
                float c = e[j] * inv;
                sp[j][0] += c * bflo(uh[j].x);
                sp[j][1] += c * bfhi(uh[j].x);
                sp[j][2] += c * bflo(uh[j].y);
                sp[j][3] += c * bfhi(uh[j].y);
            }
        }
        finish(sp);
    }

    if (tid < 160) out[b * 160 + tid] = v_sh[tid];
}

extern "C" void kernel_launch(void* const* d_in, const int* in_sizes, int n_in,
                              void* d_out, int out_size, void* d_ws, size_t ws_size,
                              hipStream_t stream) {
    const float* input = (const float*)d_in[0];
    const float* c1w = (const float*)d_in[1];
    const float* c1b = (const float*)d_in[2];
    const float* c2w = (const float*)d_in[3];
    const float* c2b = (const float*)d_in[4];
    const float* capW = (const float*)d_in[5];
    float* out = (float*)d_out;

    // ws layout (bytes):
    //   [0)            u fp32 [512][9216] (conv2 slice 0 + bias)  18,874,368
    //   [+18874368)    part1 fp32                                 18,874,368
    //   [+37748736)    Wb bf16 [1152][1280]                        2,949,120
    //   [+43122688)    region B: Wt2 (11.0 MB) + h1n (104.9 MB) + part2,3 (37.7 MB)
    //                  uhat chunk (256 x 360 KB = 92.2 MB) reuses [B_OFF, B_OFF+115.9MB)
    //                  = the DEAD Wt2+h1n region only; part2,3 stay live for uhat reads.
    const size_t U_OFF = 0;
    const size_t P1_OFF = 18874368;
    const size_t WB_OFF = 37748736;
    const size_t B_OFF = 43122688;
    const size_t WT2_BYTES = (size_t)84 * 65536 * 2;       // 11,010,048
    const size_t H1N_BYTES = 104857600;
    const size_t PART_BYTES = (size_t)PART_FLOATS * 4;     // 18,874,368
    const size_t CONV_BYTES = WT2_BYTES + H1N_BYTES + 2 * PART_BYTES;  // 153.6 MB
    if (ws_size < B_OFF + CONV_BYTES) return;

    char* wsb = (char*)d_ws;
    float* u_buf = (float*)(wsb + U_OFF);
    float* part1 = (float*)(wsb + P1_OFF);
    unsigned short* Wb = (unsigned short*)(wsb + WB_OFF);
    unsigned short* Wt2 = (unsigned short*)(wsb + B_OFF);
    unsigned short* h1n = (unsigned short*)(wsb + B_OFF + WT2_BYTES);
    float* part23 = (float*)(wsb + B_OFF + WT2_BYTES + H1N_BYTES);
    unsigned short* uhatb = (unsigned short*)(wsb + B_OFF);   // aliases dead Wt2+h1n

    wcap_k<<<1440, 256, 0, stream>>>(capW, Wb);
    wt2_k<<<256, 256, 0, stream>>>(c2w, Wt2);
    conv1_k<<<dim3(512, 4), 256, 0, stream>>>(input, c1w, c1b, h1n);
    conv2_k<<<dim3(144, 2, 4), 256, 0, stream>>>(h1n, Wt2, c2b, u_buf, part1, part23);

    const int Cr = 256;   // 256 x 360 KB = 92.2 MB <= 115.9 MB dead region
    for (int b0 = 0; b0 < 512; b0 += Cr) {
        uhat_k<<<dim3(18, Cr / 8), 256, 0, stream>>>(
            u_buf + (size_t)b0 * 9216, part1 + (size_t)b0 * 9216,
            part23 + (size_t)b0 * 9216, Wb, uhatb);
        route_k<<<Cr, 256, 0, stream>>>(uhatb, out + (size_t)b0 * 160);
    }
}

// Round 15
// 724.383 us; speedup vs baseline: 1.2111x; 1.2111x over previous
//
#include <hip/hip_runtime.h>
#include <hip/hip_bf16.h>

typedef __attribute__((ext_vector_type(8))) short bf16x8;
typedef __attribute__((ext_vector_type(4))) float f32x4;

static __device__ __forceinline__ unsigned short f2bf(float x) {
    __hip_bfloat16 h = __float2bfloat16(x);
    return *(unsigned short*)&h;
}
static __device__ __forceinline__ float bflo(unsigned int w) { return __uint_as_float(w << 16); }
static __device__ __forceinline__ float bfhi(unsigned int w) { return __uint_as_float(w & 0xffff0000u); }
static __device__ __forceinline__ float bf1(unsigned short u) { return __uint_as_float(((unsigned int)u) << 16); }

// async global->LDS DMA, 16B per lane, dest = wave-uniform base + lane*16
typedef __attribute__((address_space(1))) const void gvoid;
typedef __attribute__((address_space(3))) void lvoid;
static __device__ __forceinline__ void gl_lds16(const void* g, void* l) {
    __builtin_amdgcn_global_load_lds((gvoid*)g, (lvoid*)l, 16, 0, 0);
}

#define PART_FLOATS 4718592   // 512*9216

// ---------------- conv1 + ReLU: [512,1,28,28] -> h1n NHWC bf16 [512,20,20,256] ----------
// R25: R13's verified fp32 structure, minus the wr[81] register cache. R24's MFMA port
// FAILED (307us, MfmaUtil 1.4%, 1.6M bank conflicts -- pure im2col scatter cost).
// Old version: 132 VGPR (wr81+acc20+r28) -> ~3 waves/SIMD, can't hide the 63 float4
// LDS loads/thread. Now weights read from LDS in-loop: same-co lanes broadcast (free),
// distinct co addrs 324 B apart -> bank 17 apart -> conflict-free. 1 LDS read per
// 20 FMAs = ~5% issue cost; VGPR ~70 -> 6-8 waves/SIMD. #pragma unroll 1 on ky stops
// the compiler re-hoisting all 81 reads into registers.
__global__ __launch_bounds__(320) void conv1_k(const float* __restrict__ in,
                                               const float* __restrict__ w,
                                               const float* __restrict__ bias,
                                               unsigned short* __restrict__ h1n) {
    int blk = blockIdx.x;
    int b = blk >> 4;
    int c0 = (blk & 15) * 16;
    __shared__ float img[784];
    __shared__ float wl[16 * 81];
    __shared__ float bl[16];
    __shared__ unsigned short tr[20 * 328];
    int tid = threadIdx.x;
    for (int t = tid; t < 784; t += 320) img[t] = in[b * 784 + t];
    for (int t = tid; t < 1296; t += 320) wl[t] = w[c0 * 81 + t];
    if (tid < 16) bl[tid] = bias[c0 + tid];
    __syncthreads();

    int co = tid / 20, oy = tid % 20;
    const float* wrow = &wl[co * 81];
    float acc[20];
    float bv = bl[co];
#pragma unroll
    for (int ox = 0; ox < 20; ox++) acc[ox] = bv;

#pragma unroll 1
    for (int ky = 0; ky < 9; ky++) {
        const float* rp = &img[(oy + ky) * 28];
        float r[28];
#pragma unroll
        for (int v = 0; v < 7; v++) {
            float4 t4 = ((const float4*)rp)[v];
            r[v * 4 + 0] = t4.x; r[v * 4 + 1] = t4.y;
            r[v * 4 + 2] = t4.z; r[v * 4 + 3] = t4.w;
        }
#pragma unroll
        for (int kx = 0; kx < 9; kx++) {
            float wv = wrow[ky * 9 + kx];
#pragma unroll
            for (int ox = 0; ox < 20; ox++) acc[ox] += r[ox + kx] * wv;
        }
    }
#pragma unroll
    for (int ox = 0; ox < 20; ox++)
        tr[oy * 328 + ox * 16 + co] = f2bf(fmaxf(acc[ox], 0.f));
    __syncthreads();
    for (int g = tid; g < 800; g += 320) {
        int p = g >> 1, half = g & 1;
        uint4 v = *(uint4*)&tr[(p / 20) * 328 + (p % 20) * 16 + half * 8];
        *(uint4*)&h1n[(b * 400 + p) * 256 + c0 + half * 8] = v;
    }
}

// ---------------- W2 transpose (84 kk planes; 81..83 zeroed for uniform split-K 4) -------
// R23: one coalesced float4 pass -> bf16 LDS [cin][84] -> vectorized plane writes.
__global__ __launch_bounds__(256) void wt2_k(const float* __restrict__ w2,
                                             unsigned short* __restrict__ Wt2) {
    int cout = blockIdx.x;
    int tid = threadIdx.x;
    __shared__ unsigned short lw[256 * 84];   // 43 KB
    lw[tid * 84 + 81] = 0; lw[tid * 84 + 82] = 0; lw[tid * 84 + 83] = 0;
    const float4* src = (const float4*)(w2 + (size_t)cout * 20736);
    for (int t = tid; t < 5184; t += 256) {
        float4 v = src[t];
        int flat = t * 4;
#pragma unroll
        for (int e = 0; e < 4; e++) {
            int f = flat + e;
            int cin = f / 81, kk = f - cin * 81;
            float x = (e == 0) ? v.x : (e == 1) ? v.y : (e == 2) ? v.z : v.w;
            lw[cin * 84 + kk] = f2bf(x);
        }
    }
    __syncthreads();
    int kko = tid >> 7, c2 = (tid & 127) * 2;
    for (int base = 0; base < 84; base += 2) {
        int kk = base + kko;
        unsigned int val = (unsigned int)lw[c2 * 84 + kk]
                         | ((unsigned int)lw[(c2 + 1) * 84 + kk] << 16);
        *(unsigned int*)&Wt2[(size_t)kk * 65536 + cout * 256 + c2] = val;
    }
}

// ---------------- capW f32 -> bf16 (same flat layout i*1280 + j*128 + p*16 + q) ----------
__global__ __launch_bounds__(256) void wcap_k(const float* __restrict__ W,
                                              unsigned short* __restrict__ Wb) {
    int idx4 = blockIdx.x * 256 + threadIdx.x;   // 368,640 total (1,474,560 / 4)
    float4 v = *(const float4*)&W[(size_t)idx4 * 4];
    unsigned int lo = (unsigned int)f2bf(v.x) | ((unsigned int)f2bf(v.y) << 16);
    unsigned int hi = (unsigned int)f2bf(v.z) | ((unsigned int)f2bf(v.w) << 16);
    uint2 pk; pk.x = lo; pk.y = hi;
    *(uint2*)&Wb[(size_t)idx4 * 4] = pk;
}

// ---------------- conv2 implicit GEMM, bf16 MFMA, 128x128, split-K 4 ---------------------
// R12 (verified best, ~278-294us, SESSION CEILING for this structure): 2-phase double-
// buffered global_load_lds prefetch; one barrier per round; XOR swizzle via pre-swizzled
// SOURCE (rule 21). 64 KB LDS -> 2 blocks/CU.
// Failed alternatives: R16 direct-B regs (540us); R17 BK=32 (294); R18 counted-vmcnt on
// 2-phase (333); R21 XCD decode (299, FETCH 2.4x -> latency-bound proof); R22 BN=256
// 3-ring (360, 1 blk/CU killed TLP).
__global__ __launch_bounds__(256) void conv2_k(const unsigned short* __restrict__ h1n,
                                               const unsigned short* __restrict__ Wt2,
                                               const float* __restrict__ bias,
                                               float* __restrict__ u,
                                               float* __restrict__ part1,
                                               float* __restrict__ part23) {
    __shared__ unsigned short sA[2][128 * 64];   // 32 KB, XOR-swizzled, double-buffered
    __shared__ unsigned short sB[2][128 * 64];   // 32 KB, XOR-swizzled, double-buffered
    int tid = threadIdx.x;
    int m0 = blockIdx.x * 128;
    int n0 = blockIdx.y * 128;
    int slice = blockIdx.z;
    int ks = slice * 21;

    int wv = tid >> 6, lane = tid & 63;
    int wm = wv >> 1, wn = wv & 1;
    int lr = lane & 15, quad = lane >> 4;

    // staging geometry (per wave): 4 instrs for A + 4 for B, 8 rows per instr
    int lrow = lane >> 3, lslot = lane & 7;
    int kcoff = (lslot ^ lrow) * 8;           // pre-swizzled chunk offset (shorts)
    int aG[4], bG[4];
#pragma unroll
    for (int t = 0; t < 4; t++) {
        int r = wv * 32 + t * 8 + lrow;       // sA/sB row this lane feeds in instr t
        int R = m0 + r;
        int b = R / 36, m = R % 36;
        int oy = m / 6, ox = m % 6;
        aG[t] = b * 102400 + oy * 10240 + ox * 512 + kcoff;
        bG[t] = (n0 + r) * 256 + kcoff;
    }

    f32x4 acc[4][4];
#pragma unroll
    for (int i = 0; i < 4; i++)
#pragma unroll
        for (int j = 0; j < 4; j++) acc[i][j] = (f32x4){0.f, 0.f, 0.f, 0.f};

    auto stage = [&](int buf, int rr) {
        int kk = ks + (rr >> 2), cr = rr & 3;      // wave-uniform -> SALU
        int ky = kk / 9, kx = kk % 9;
        int aoff = ky * 5120 + kx * 256 + cr * 64;
        int boff = kk * 65536 + cr * 64;
        unsigned short* dA = &sA[buf][wv * 2048];
        unsigned short* dB = &sB[buf][wv * 2048];
#pragma unroll
        for (int t = 0; t < 4; t++)
            gl_lds16(h1n + aG[t] + aoff, dA + t * 512);
#pragma unroll
        for (int t = 0; t < 4; t++)
            gl_lds16(Wt2 + bG[t] + boff, dB + t * 512);
    };

    // prologue: fill buf0, drain, barrier
    stage(0, 0);
    __syncthreads();

    int cur = 0;
#pragma unroll 1
    for (int rr = 0; rr < 84; rr++) {
        if (rr < 83) stage(cur ^ 1, rr + 1);   // prefetch next round (stays in flight)
        const unsigned short* pA = &sA[cur][0];
        const unsigned short* pB = &sB[cur][0];
#pragma unroll
        for (int s = 0; s < 2; s++) {
            bf16x8 af[4], bf[4];
#pragma unroll
            for (int i = 0; i < 4; i++) {
                int arow = wm * 64 + i * 16 + lr;
                af[i] = *(bf16x8*)&pA[arow * 64 + 8 * ((s * 4 + quad) ^ (lr & 7))];
            }
#pragma unroll
            for (int j = 0; j < 4; j++) {
                int brow = wn * 64 + j * 16 + lr;
                bf[j] = *(bf16x8*)&pB[brow * 64 + 8 * ((s * 4 + quad) ^ (lr & 7))];
            }
#pragma unroll
            for (int i = 0; i < 4; i++)
#pragma unroll
                for (int j = 0; j < 4; j++)
                    acc[i][j] = __builtin_amdgcn_mfma_f32_16x16x32_bf16(
                        af[i], bf[j], acc[i][j], 0, 0, 0);
        }
        __syncthreads();   // drains prefetch vmcnt(0); it had the whole compute to land
        cur ^= 1;
    }

    // epilogue: C/D layout col=lane&15, row=quad*4+reg
    float* dst = (slice == 0) ? u : ((slice == 1) ? part1 : part23 + (size_t)(slice - 2) * PART_FLOATS);
#pragma unroll
    for (int j = 0; j < 4; j++) {
        int col = n0 + wn * 64 + j * 16 + lr;
        float bv = (slice == 0) ? bias[col] : 0.f;
#pragma unroll
        for (int i = 0; i < 4; i++) {
#pragma unroll
            for (int rg = 0; rg < 4; rg++) {
                int RR = m0 + wm * 64 + i * 16 + quad * 4 + rg;
                int bb = RR / 36, mm = RR % 36;
                int oyy = mm / 6, oxx = mm % 6;
                dst[bb * 9216 + oxx * 1536 + oyy * 256 + col] = acc[i][j][rg] + bv;
            }
        }
    }
}

// ---------------- u_hat: (u+p1+p2+p3)[b,i,p] x Wb[i,j,p,q] -> uhat bf16 [b][j][i*16+q] --
// R20 (verified): add-fold (190 MB add pass gone) + bf16 W (wl 16.6 KB) + 8 samples/
// block + float4 x 4-stream staging. LDS 18.4+16.6 = 35 KB -> 4 blocks/CU.
__global__ __launch_bounds__(256) void uhat_k(const float* __restrict__ u,
                                              const float* __restrict__ p1,
                                              const float* __restrict__ p23,
                                              const unsigned short* __restrict__ Wb,
                                              unsigned short* __restrict__ uhat) {
    int i0 = blockIdx.x * 64;
    int b0 = blockIdx.y * 8;      // LOCAL sample index within this chunk
    __shared__ float ul[8 * 576];           // [bb][il*9+p], 18.4 KB
    __shared__ unsigned short wl[64 * 130]; // 16.6 KB
    int tid = threadIdx.x;

    // fold-staging: 1024 float4-groups (8 bb x 128), 4 iterations/thread
    for (int t = tid; t < 1024; t += 256) {
        int bb = t >> 7, rq = t & 127;
        int r = rq * 4;
        size_t gidx = (size_t)(b0 + bb) * 9216 + i0 * 8 + r;
        float4 a = *(const float4*)&u[gidx];
        float4 x = *(const float4*)&p1[gidx];
        float4 y = *(const float4*)&p23[gidx];
        float4 z = *(const float4*)&p23[PART_FLOATS + gidx];
        float* d = &ul[bb * 576 + (r >> 3) * 9 + (r & 7)];
        d[0] = a.x + x.x + y.x + z.x;
        d[1] = a.y + x.y + y.y + z.y;
        d[2] = a.z + x.z + y.z + z.z;
        d[3] = a.w + x.w + y.w + z.w;
    }

    int il = tid & 63, g = tid >> 6;
    for (int j = 0; j < 10; j++) {
        __syncthreads();
        for (int t = tid; t < 4096; t += 256) {
            int li = t >> 6, cp = t & 63;   // 64 uint (2 bf16) per 128-col row
            *(unsigned int*)&wl[li * 130 + cp * 2] =
                *(const unsigned int*)&Wb[(size_t)(i0 + li) * 1280 + j * 128 + cp * 2];
        }
        __syncthreads();
#pragma unroll 1
        for (int bb = 0; bb < 8; bb++) {
            float ur[8];
#pragma unroll
            for (int p = 0; p < 8; p++) ur[p] = ul[bb * 576 + il * 9 + p];
            float a[4];
#pragma unroll
            for (int k = 0; k < 4; k++) {
                int q = g * 4 + k;
                float s = 0.f;
#pragma unroll
                for (int p = 0; p < 8; p++) s += ur[p] * bf1(wl[il * 130 + p * 16 + q]);
                a[k] = s;
            }
            unsigned int lo = (unsigned int)f2bf(a[0]) | ((unsigned int)f2bf(a[1]) << 16);
            unsigned int hi = (unsigned int)f2bf(a[2]) | ((unsigned int)f2bf(a[3]) << 16);
            uint2 pk; pk.x = lo; pk.y = hi;
            *(uint2*)&uhat[((size_t)(b0 + bb) * 10 + j) * 18432 + (size_t)(i0 + il) * 16 + g * 4] = pk;
        }
    }
}

// ---------------- fused dynamic routing: one block per batch sample ----------------------
// R13 (verified): b_ij in LDS, s/v in LDS, zero global atomics, no inter-kernel drains.
// uhat[b] (360 KB, L2/L3-resident) streamed 3x. R14: [b][j][i16q] layout -> 512 B
// contiguous per wave per j.
__global__ __launch_bounds__(256) void route_k(const unsigned short* __restrict__ uhat,
                                               float* __restrict__ out) {
    int b = blockIdx.x;
    int tid = threadIdx.x;
    int w = tid >> 6, lane = tid & 63;
    int ig = lane >> 2, qh = lane & 3;
    __shared__ float b_sh[1152 * 10];   // 46 KB
    __shared__ float s_red[4 * 160];
    __shared__ float v_sh[160];
    __shared__ float sc_sh[10];
    const unsigned short* ub = uhat + (size_t)b * 184320;

    float v_ln[10][4];   // this lane's v[j*16 + qh*4 + k]

    // reduce sp -> s -> squash -> v_sh -> v_ln  (shared tail for every pass)
    auto finish = [&](float sp[10][4]) {
#pragma unroll
        for (int j = 0; j < 10; j++)
#pragma unroll
            for (int k = 0; k < 4; k++) {
                float t = sp[j][k];
                t += __shfl_xor(t, 4);
                t += __shfl_xor(t, 8);
                t += __shfl_xor(t, 16);
                t += __shfl_xor(t, 32);
                sp[j][k] = t;
            }
        if (ig == 0) {   // lanes 0..3 of each wave hold the wave totals
#pragma unroll
            for (int j = 0; j < 10; j++) {
                f32x4 v4 = {sp[j][0], sp[j][1], sp[j][2], sp[j][3]};
                *(f32x4*)&s_red[w * 160 + j * 16 + qh * 4] = v4;
            }
        }
        __syncthreads();
        if (tid < 160) {
            float s = s_red[tid] + s_red[160 + tid] + s_red[320 + tid] + s_red[480 + tid];
            s_red[tid] = s;
        }
        __syncthreads();
        if (tid < 10) {
            float sq = 0.f;
#pragma unroll
            for (int q = 0; q < 16; q++) { float x = s_red[tid * 16 + q]; sq += x * x; }
            float norm = sqrtf(sq + 1e-8f);
            sc_sh[tid] = (sq / (1.0f + sq)) / norm;
        }
        __syncthreads();
        if (tid < 160) v_sh[tid] = s_red[tid] * sc_sh[tid >> 4];
        __syncthreads();
#pragma unroll
        for (int j = 0; j < 10; j++) {
            f32x4 v4 = *(const f32x4*)&v_sh[j * 16 + qh * 4];
            v_ln[j][0] = v4[0]; v_ln[j][1] = v4[1]; v_ln[j][2] = v4[2]; v_ln[j][3] = v4[3];
        }
        __syncthreads();
    };

    // ---- pass 1: c = 0.1 uniform ----
    {
        float sp[10][4];
#pragma unroll
        for (int j = 0; j < 10; j++)
#pragma unroll
            for (int k = 0; k < 4; k++) sp[j][k] = 0.f;
#pragma unroll 2
        for (int r = 0; r < 18; r++) {
            int i = r * 64 + w * 16 + ig;
            const unsigned short* up = ub + (size_t)i * 16 + qh * 4;
            uint2 uh[10];
#pragma unroll
            for (int j = 0; j < 10; j++) uh[j] = *(const uint2*)(up + (size_t)j * 18432);
#pragma unroll
            for (int j = 0; j < 10; j++) {
                sp[j][0] += 0.1f * bflo(uh[j].x);
                sp[j][1] += 0.1f * bfhi(uh[j].x);
                sp[j][2] += 0.1f * bflo(uh[j].y);
                sp[j][3] += 0.1f * bfhi(uh[j].y);
            }
        }
        finish(sp);
    }

    // ---- passes 2,3: delta = uhat.v, b update, softmax, s-accumulate ----
#pragma unroll 1
    for (int pass = 0; pass < 2; pass++) {
        bool first = (pass == 0);    // pass2: b_prev = 0, write b_sh; pass3: read b_sh
        float sp[10][4];
#pragma unroll
        for (int j = 0; j < 10; j++)
#pragma unroll
            for (int k = 0; k < 4; k++) sp[j][k] = 0.f;
#pragma unroll 2
        for (int r = 0; r < 18; r++) {
            int i = r * 64 + w * 16 + ig;
            const unsigned short* up = ub + (size_t)i * 16 + qh * 4;
            uint2 uh[10];
#pragma unroll
            for (int j = 0; j < 10; j++) uh[j] = *(const uint2*)(up + (size_t)j * 18432);
            float d[10];
#pragma unroll
            for (int j = 0; j < 10; j++) {
                d[j] = bflo(uh[j].x) * v_ln[j][0] + bfhi(uh[j].x) * v_ln[j][1]
                     + bflo(uh[j].y) * v_ln[j][2] + bfhi(uh[j].y) * v_ln[j][3];
            }
#pragma unroll
            for (int j = 0; j < 10; j++) {
                d[j] += __shfl_xor(d[j], 1);
                d[j] += __shfl_xor(d[j], 2);
            }
            float bn[10];
            if (first) {
#pragma unroll
                for (int j = 0; j < 10; j++) bn[j] = d[j];
#pragma unroll
                for (int j = 0; j < 10; j++)
                    if (qh == (j & 3)) b_sh[i * 10 + j] = bn[j];
            } else {
#pragma unroll
                for (int j = 0; j < 10; j++) bn[j] = b_sh[i * 10 + j] + d[j];
            }
            float m = bn[0];
#pragma unroll
            for (int j = 1; j < 10; j++) m = fmaxf(m, bn[j]);
            float e[10], sum = 0.f;
#pragma unroll
            for (int j = 0; j < 10; j++) { e[j] = __expf(bn[j] - m); sum += e[j]; }
            float inv = 1.f / sum;
#pragma unroll
            for (int j = 0; j < 10; j++) {
                float c = e[j] * inv;
                sp[j][0] += c * bflo(uh[j].x);
                sp[j][1] += c * bfhi(uh[j].x);
                sp[j][2] += c * bflo(uh[j].y);
                sp[j][3] += c * bfhi(uh[j].y);
            }
        }
        finish(sp);
    }

    if (tid < 160) out[b * 160 + tid] = v_sh[tid];
}

extern "C" void kernel_launch(void* const* d_in, const int* in_sizes, int n_in,
                              void* d_out, int out_size, void* d_ws, size_t ws_size,
                              hipStream_t stream) {
    const float* input = (const float*)d_in[0];
    const float* c1w = (const float*)d_in[1];
    const float* c1b = (const float*)d_in[2];
    const float* c2w = (const float*)d_in[3];
    const float* c2b = (const float*)d_in[4];
    const float* capW = (const float*)d_in[5];
    float* out = (float*)d_out;

    // ws layout (bytes):
    //   [0)            u fp32 [512][9216] (conv2 slice 0 + bias)  18,874,368
    //   [+18874368)    part1 fp32                                 18,874,368
    //   [+37748736)    Wb bf16 [1152][1280]                        2,949,120
    //   [+43122688)    region B: Wt2 (11.0 MB) + h1n (104.9 MB) + part2,3 (37.7 MB)
    //                  uhat chunk (256 x 360 KB = 92.2 MB) reuses [B_OFF, B_OFF+115.9MB)
    //                  = the DEAD Wt2+h1n region only; part2,3 stay live for uhat reads.
    const size_t U_OFF = 0;
    const size_t P1_OFF = 18874368;
    const size_t WB_OFF = 37748736;
    const size_t B_OFF = 43122688;
    const size_t WT2_BYTES = (size_t)84 * 65536 * 2;       // 11,010,048
    const size_t H1N_BYTES = 104857600;
    const size_t PART_BYTES = (size_t)PART_FLOATS * 4;     // 18,874,368
    const size_t CONV_BYTES = WT2_BYTES + H1N_BYTES + 2 * PART_BYTES;  // 153.6 MB
    if (ws_size < B_OFF + CONV_BYTES) return;

    char* wsb = (char*)d_ws;
    float* u_buf = (float*)(wsb + U_OFF);
    float* part1 = (float*)(wsb + P1_OFF);
    unsigned short* Wb = (unsigned short*)(wsb + WB_OFF);
    unsigned short* Wt2 = (unsigned short*)(wsb + B_OFF);
    unsigned short* h1n = (unsigned short*)(wsb + B_OFF + WT2_BYTES);
    float* part23 = (float*)(wsb + B_OFF + WT2_BYTES + H1N_BYTES);
    unsigned short* uhatb = (unsigned short*)(wsb + B_OFF);   // aliases dead Wt2+h1n

    wcap_k<<<1440, 256, 0, stream>>>(capW, Wb);
    wt2_k<<<256, 256, 0, stream>>>(c2w, Wt2);
    conv1_k<<<512 * 16, 320, 0, stream>>>(input, c1w, c1b, h1n);
    conv2_k<<<dim3(144, 2, 4), 256, 0, stream>>>(h1n, Wt2, c2b, u_buf, part1, part23);

    const int Cr = 256;   // 256 x 360 KB = 92.2 MB <= 115.9 MB dead region
    for (int b0 = 0; b0 < 512; b0 += Cr) {
        uhat_k<<<dim3(18, Cr / 8), 256, 0, stream>>>(
            u_buf + (size_t)b0 * 9216, part1 + (size_t)b0 * 9216,
            part23 + (size_t)b0 * 9216, Wb, uhatb);
        route_k<<<Cr, 256, 0, stream>>>(uhatb, out + (size_t)b0 * 160);
    }
}

// Round 16
// 692.460 us; speedup vs baseline: 1.2669x; 1.0461x over previous
//
#include <hip/hip_runtime.h>
#include <hip/hip_bf16.h>

typedef __attribute__((ext_vector_type(8))) short bf16x8;
typedef __attribute__((ext_vector_type(4))) float f32x4;

static __device__ __forceinline__ unsigned short f2bf(float x) {
    __hip_bfloat16 h = __float2bfloat16(x);
    return *(unsigned short*)&h;
}
static __device__ __forceinline__ float bflo(unsigned int w) { return __uint_as_float(w << 16); }
static __device__ __forceinline__ float bfhi(unsigned int w) { return __uint_as_float(w & 0xffff0000u); }
static __device__ __forceinline__ float bf1(unsigned short u) { return __uint_as_float(((unsigned int)u) << 16); }

// async global->LDS DMA, 16B per lane, dest = wave-uniform base + lane*16
typedef __attribute__((address_space(1))) const void gvoid;
typedef __attribute__((address_space(3))) void lvoid;
static __device__ __forceinline__ void gl_lds16(const void* g, void* l) {
    __builtin_amdgcn_global_load_lds((gvoid*)g, (lvoid*)l, 16, 0, 0);
}

#define PART_FLOATS 4718592   // 512*9216

// ---------------- conv1 + ReLU: [512,1,28,28] -> h1n NHWC bf16 [512,20,20,256] ----------
// R13-verified fp32 structure (wr[81] register cache). Alternatives falsified:
// R24 MFMA port (307us: MfmaUtil 1.4%, im2col scatter cost); R25 LDS-weights
// (+18us: LDS pipe is co-binding with VALU -- 63 b128 reads/thread ~ 50us floor vs
// 54us FMA floor; adding weight reads to LDS pressured the shared pipe).
__global__ __launch_bounds__(320) void conv1_k(const float* __restrict__ in,
                                               const float* __restrict__ w,
                                               const float* __restrict__ bias,
                                               unsigned short* __restrict__ h1n) {
    int blk = blockIdx.x;
    int b = blk >> 4;
    int c0 = (blk & 15) * 16;
    __shared__ float img[784];
    __shared__ float wl[16 * 81];
    __shared__ float bl[16];
    __shared__ unsigned short tr[20 * 328];
    int tid = threadIdx.x;
    for (int t = tid; t < 784; t += 320) img[t] = in[b * 784 + t];
    for (int t = tid; t < 1296; t += 320) wl[t] = w[c0 * 81 + t];
    if (tid < 16) bl[tid] = bias[c0 + tid];
    __syncthreads();

    int co = tid / 20, oy = tid % 20;
    float wr[81];
#pragma unroll
    for (int k = 0; k < 81; k++) wr[k] = wl[co * 81 + k];
    float acc[20];
    float bv = bl[co];
#pragma unroll
    for (int ox = 0; ox < 20; ox++) acc[ox] = bv;

#pragma unroll
    for (int ky = 0; ky < 9; ky++) {
        const float* rp = &img[(oy + ky) * 28];
        float r[28];
#pragma unroll
        for (int v = 0; v < 7; v++) {
            float4 t4 = ((const float4*)rp)[v];
            r[v * 4 + 0] = t4.x; r[v * 4 + 1] = t4.y;
            r[v * 4 + 2] = t4.z; r[v * 4 + 3] = t4.w;
        }
#pragma unroll
        for (int kx = 0; kx < 9; kx++) {
            float wv = wr[ky * 9 + kx];
#pragma unroll
            for (int ox = 0; ox < 20; ox++) acc[ox] += r[ox + kx] * wv;
        }
    }
#pragma unroll
    for (int ox = 0; ox < 20; ox++)
        tr[oy * 328 + ox * 16 + co] = f2bf(fmaxf(acc[ox], 0.f));
    __syncthreads();
    for (int g = tid; g < 800; g += 320) {
        int p = g >> 1, half = g & 1;
        uint4 v = *(uint4*)&tr[(p / 20) * 328 + (p % 20) * 16 + half * 8];
        *(uint4*)&h1n[(b * 400 + p) * 256 + c0 + half * 8] = v;
    }
}

// ---------------- W2 transpose (84 kk planes; 81..83 zeroed for uniform split-K 4) -------
// R23: one coalesced float4 pass -> bf16 LDS [cin][84] -> vectorized plane writes.
__global__ __launch_bounds__(256) void wt2_k(const float* __restrict__ w2,
                                             unsigned short* __restrict__ Wt2) {
    int cout = blockIdx.x;
    int tid = threadIdx.x;
    __shared__ unsigned short lw[256 * 84];   // 43 KB
    lw[tid * 84 + 81] = 0; lw[tid * 84 + 82] = 0; lw[tid * 84 + 83] = 0;
    const float4* src = (const float4*)(w2 + (size_t)cout * 20736);
    for (int t = tid; t < 5184; t += 256) {
        float4 v = src[t];
        int flat = t * 4;
#pragma unroll
        for (int e = 0; e < 4; e++) {
            int f = flat + e;
            int cin = f / 81, kk = f - cin * 81;
            float x = (e == 0) ? v.x : (e == 1) ? v.y : (e == 2) ? v.z : v.w;
            lw[cin * 84 + kk] = f2bf(x);
        }
    }
    __syncthreads();
    int kko = tid >> 7, c2 = (tid & 127) * 2;
    for (int base = 0; base < 84; base += 2) {
        int kk = base + kko;
        unsigned int val = (unsigned int)lw[c2 * 84 + kk]
                         | ((unsigned int)lw[(c2 + 1) * 84 + kk] << 16);
        *(unsigned int*)&Wt2[(size_t)kk * 65536 + cout * 256 + c2] = val;
    }
}

// ---------------- capW f32 -> bf16 (same flat layout i*1280 + j*128 + p*16 + q) ----------
__global__ __launch_bounds__(256) void wcap_k(const float* __restrict__ W,
                                              unsigned short* __restrict__ Wb) {
    int idx4 = blockIdx.x * 256 + threadIdx.x;   // 368,640 total (1,474,560 / 4)
    float4 v = *(const float4*)&W[(size_t)idx4 * 4];
    unsigned int lo = (unsigned int)f2bf(v.x) | ((unsigned int)f2bf(v.y) << 16);
    unsigned int hi = (unsigned int)f2bf(v.z) | ((unsigned int)f2bf(v.w) << 16);
    uint2 pk; pk.x = lo; pk.y = hi;
    *(uint2*)&Wb[(size_t)idx4 * 4] = pk;
}

// ---------------- conv2 implicit GEMM, bf16 MFMA, 128x128, split-K 4 ---------------------
// R12 (verified best, ~278-294us, SESSION CEILING for this structure): 2-phase double-
// buffered global_load_lds prefetch; one barrier per round; XOR swizzle via pre-swizzled
// SOURCE (rule 21). 64 KB LDS -> 2 blocks/CU.
// Failed alternatives: R16 direct-B regs (540us); R17 BK=32 (294); R18 counted-vmcnt on
// 2-phase (333); R21 XCD decode (299, FETCH 2.4x -> latency-bound proof); R22 BN=256
// 3-ring (360, 1 blk/CU killed TLP).
__global__ __launch_bounds__(256) void conv2_k(const unsigned short* __restrict__ h1n,
                                               const unsigned short* __restrict__ Wt2,
                                               const float* __restrict__ bias,
                                               float* __restrict__ u,
                                               float* __restrict__ part1,
                                               float* __restrict__ part23) {
    __shared__ unsigned short sA[2][128 * 64];   // 32 KB, XOR-swizzled, double-buffered
    __shared__ unsigned short sB[2][128 * 64];   // 32 KB, XOR-swizzled, double-buffered
    int tid = threadIdx.x;
    int m0 = blockIdx.x * 128;
    int n0 = blockIdx.y * 128;
    int slice = blockIdx.z;
    int ks = slice * 21;

    int wv = tid >> 6, lane = tid & 63;
    int wm = wv >> 1, wn = wv & 1;
    int lr = lane & 15, quad = lane >> 4;

    // staging geometry (per wave): 4 instrs for A + 4 for B, 8 rows per instr
    int lrow = lane >> 3, lslot = lane & 7;
    int kcoff = (lslot ^ lrow) * 8;           // pre-swizzled chunk offset (shorts)
    int aG[4], bG[4];
#pragma unroll
    for (int t = 0; t < 4; t++) {
        int r = wv * 32 + t * 8 + lrow;       // sA/sB row this lane feeds in instr t
        int R = m0 + r;
        int b = R / 36, m = R % 36;
        int oy = m / 6, ox = m % 6;
        aG[t] = b * 102400 + oy * 10240 + ox * 512 + kcoff;
        bG[t] = (n0 + r) * 256 + kcoff;
    }

    f32x4 acc[4][4];
#pragma unroll
    for (int i = 0; i < 4; i++)
#pragma unroll
        for (int j = 0; j < 4; j++) acc[i][j] = (f32x4){0.f, 0.f, 0.f, 0.f};

    auto stage = [&](int buf, int rr) {
        int kk = ks + (rr >> 2), cr = rr & 3;      // wave-uniform -> SALU
        int ky = kk / 9, kx = kk % 9;
        int aoff = ky * 5120 + kx * 256 + cr * 64;
        int boff = kk * 65536 + cr * 64;
        unsigned short* dA = &sA[buf][wv * 2048];
        unsigned short* dB = &sB[buf][wv * 2048];
#pragma unroll
        for (int t = 0; t < 4; t++)
            gl_lds16(h1n + aG[t] + aoff, dA + t * 512);
#pragma unroll
        for (int t = 0; t < 4; t++)
            gl_lds16(Wt2 + bG[t] + boff, dB + t * 512);
    };

    // prologue: fill buf0, drain, barrier
    stage(0, 0);
    __syncthreads();

    int cur = 0;
#pragma unroll 1
    for (int rr = 0; rr < 84; rr++) {
        if (rr < 83) stage(cur ^ 1, rr + 1);   // prefetch next round (stays in flight)
        const unsigned short* pA = &sA[cur][0];
        const unsigned short* pB = &sB[cur][0];
#pragma unroll
        for (int s = 0; s < 2; s++) {
            bf16x8 af[4], bf[4];
#pragma unroll
            for (int i = 0; i < 4; i++) {
                int arow = wm * 64 + i * 16 + lr;
                af[i] = *(bf16x8*)&pA[arow * 64 + 8 * ((s * 4 + quad) ^ (lr & 7))];
            }
#pragma unroll
            for (int j = 0; j < 4; j++) {
                int brow = wn * 64 + j * 16 + lr;
                bf[j] = *(bf16x8*)&pB[brow * 64 + 8 * ((s * 4 + quad) ^ (lr & 7))];
            }
#pragma unroll
            for (int i = 0; i < 4; i++)
#pragma unroll
                for (int j = 0; j < 4; j++)
                    acc[i][j] = __builtin_amdgcn_mfma_f32_16x16x32_bf16(
                        af[i], bf[j], acc[i][j], 0, 0, 0);
        }
        __syncthreads();   // drains prefetch vmcnt(0); it had the whole compute to land
        cur ^= 1;
    }

    // epilogue: C/D layout col=lane&15, row=quad*4+reg
    float* dst = (slice == 0) ? u : ((slice == 1) ? part1 : part23 + (size_t)(slice - 2) * PART_FLOATS);
#pragma unroll
    for (int j = 0; j < 4; j++) {
        int col = n0 + wn * 64 + j * 16 + lr;
        float bv = (slice == 0) ? bias[col] : 0.f;
#pragma unroll
        for (int i = 0; i < 4; i++) {
#pragma unroll
            for (int rg = 0; rg < 4; rg++) {
                int RR = m0 + wm * 64 + i * 16 + quad * 4 + rg;
                int bb = RR / 36, mm = RR % 36;
                int oyy = mm / 6, oxx = mm % 6;
                dst[bb * 9216 + oxx * 1536 + oyy * 256 + col] = acc[i][j][rg] + bv;
            }
        }
    }
}

// ---------------- u_hat: (u+p1+p2+p3)[b,i,p] x Wb[i,j,p,q] -> uhat bf16 [b][j][i*16+q] --
// R20 (verified): add-fold (190 MB add pass gone) + bf16 W (wl 16.6 KB) + 8 samples/
// block + float4 x 4-stream staging. LDS 18.4+16.6 = 35 KB -> 4 blocks/CU.
__global__ __launch_bounds__(256) void uhat_k(const float* __restrict__ u,
                                              const float* __restrict__ p1,
                                              const float* __restrict__ p23,
                                              const unsigned short* __restrict__ Wb,
                                              unsigned short* __restrict__ uhat) {
    int i0 = blockIdx.x * 64;
    int b0 = blockIdx.y * 8;      // LOCAL sample index within this chunk
    __shared__ float ul[8 * 576];           // [bb][il*9+p], 18.4 KB
    __shared__ unsigned short wl[64 * 130]; // 16.6 KB
    int tid = threadIdx.x;

    // fold-staging: 1024 float4-groups (8 bb x 128), 4 iterations/thread
    for (int t = tid; t < 1024; t += 256) {
        int bb = t >> 7, rq = t & 127;
        int r = rq * 4;
        size_t gidx = (size_t)(b0 + bb) * 9216 + i0 * 8 + r;
        float4 a = *(const float4*)&u[gidx];
        float4 x = *(const float4*)&p1[gidx];
        float4 y = *(const float4*)&p23[gidx];
        float4 z = *(const float4*)&p23[PART_FLOATS + gidx];
        float* d = &ul[bb * 576 + (r >> 3) * 9 + (r & 7)];
        d[0] = a.x + x.x + y.x + z.x;
        d[1] = a.y + x.y + y.y + z.y;
        d[2] = a.z + x.z + y.z + z.z;
        d[3] = a.w + x.w + y.w + z.w;
    }

    int il = tid & 63, g = tid >> 6;
    for (int j = 0; j < 10; j++) {
        __syncthreads();
        for (int t = tid; t < 4096; t += 256) {
            int li = t >> 6, cp = t & 63;   // 64 uint (2 bf16) per 128-col row
            *(unsigned int*)&wl[li * 130 + cp * 2] =
                *(const unsigned int*)&Wb[(size_t)(i0 + li) * 1280 + j * 128 + cp * 2];
        }
        __syncthreads();
#pragma unroll 1
        for (int bb = 0; bb < 8; bb++) {
            float ur[8];
#pragma unroll
            for (int p = 0; p < 8; p++) ur[p] = ul[bb * 576 + il * 9 + p];
            float a[4];
#pragma unroll
            for (int k = 0; k < 4; k++) {
                int q = g * 4 + k;
                float s = 0.f;
#pragma unroll
                for (int p = 0; p < 8; p++) s += ur[p] * bf1(wl[il * 130 + p * 16 + q]);
                a[k] = s;
            }
            unsigned int lo = (unsigned int)f2bf(a[0]) | ((unsigned int)f2bf(a[1]) << 16);
            unsigned int hi = (unsigned int)f2bf(a[2]) | ((unsigned int)f2bf(a[3]) << 16);
            uint2 pk; pk.x = lo; pk.y = hi;
            *(uint2*)&uhat[((size_t)(b0 + bb) * 10 + j) * 18432 + (size_t)(i0 + il) * 16 + g * 4] = pk;
        }
    }
}

// ---------------- fused dynamic routing: one block per batch sample ----------------------
// R13 (verified): b_ij in LDS, s/v in LDS, zero global atomics, no inter-kernel drains.
// uhat[b] (360 KB, L2/L3-resident) streamed 3x. R14: [b][j][i16q] layout -> 512 B
// contiguous per wave per j.
__global__ __launch_bounds__(256) void route_k(const unsigned short* __restrict__ uhat,
                                               float* __restrict__ out) {
    int b = blockIdx.x;
    int tid = threadIdx.x;
    int w = tid >> 6, lane = tid & 63;
    int ig = lane >> 2, qh = lane & 3;
    __shared__ float b_sh[1152 * 10];   // 46 KB
    __shared__ float s_red[4 * 160];
    __shared__ float v_sh[160];
    __shared__ float sc_sh[10];
    const unsigned short* ub = uhat + (size_t)b * 184320;

    float v_ln[10][4];   // this lane's v[j*16 + qh*4 + k]

    // reduce sp -> s -> squash -> v_sh -> v_ln  (shared tail for every pass)
    auto finish = [&](float sp[10][4]) {
#pragma unroll
        for (int j = 0; j < 10; j++)
#pragma unroll
            for (int k = 0; k < 4; k++) {
                float t = sp[j][k];
                t += __shfl_xor(t, 4);
                t += __shfl_xor(t, 8);
                t += __shfl_xor(t, 16);
                t += __shfl_xor(t, 32);
                sp[j][k] = t;
            }
        if (ig == 0) {   // lanes 0..3 of each wave hold the wave totals
#pragma unroll
            for (int j = 0; j < 10; j++) {
                f32x4 v4 = {sp[j][0], sp[j][1], sp[j][2], sp[j][3]};
                *(f32x4*)&s_red[w * 160 + j * 16 + qh * 4] = v4;
            }
        }
        __syncthreads();
        if (tid < 160) {
            float s = s_red[tid] + s_red[160 + tid] + s_red[320 + tid] + s_red[480 + tid];
            s_red[tid] = s;
        }
        __syncthreads();
        if (tid < 10) {
            float sq = 0.f;
#pragma unroll
            for (int q = 0; q < 16; q++) { float x = s_red[tid * 16 + q]; sq += x * x; }
            float norm = sqrtf(sq + 1e-8f);
            sc_sh[tid] = (sq / (1.0f + sq)) / norm;
        }
        __syncthreads();
        if (tid < 160) v_sh[tid] = s_red[tid] * sc_sh[tid >> 4];
        __syncthreads();
#pragma unroll
        for (int j = 0; j < 10; j++) {
            f32x4 v4 = *(const f32x4*)&v_sh[j * 16 + qh * 4];
            v_ln[j][0] = v4[0]; v_ln[j][1] = v4[1]; v_ln[j][2] = v4[2]; v_ln[j][3] = v4[3];
        }
        __syncthreads();
    };

    // ---- pass 1: c = 0.1 uniform ----
    {
        float sp[10][4];
#pragma unroll
        for (int j = 0; j < 10; j++)
#pragma unroll
            for (int k = 0; k < 4; k++) sp[j][k] = 0.f;
#pragma unroll 2
        for (int r = 0; r < 18; r++) {
            int i = r * 64 + w * 16 + ig;
            const unsigned short* up = ub + (size_t)i * 16 + qh * 4;
            uint2 uh[10];
#pragma unroll
            for (int j = 0; j < 10; j++) uh[j] = *(const uint2*)(up + (size_t)j * 18432);
#pragma unroll
            for (int j = 0; j < 10; j++) {
                sp[j][0] += 0.1f * bflo(uh[j].x);
                sp[j][1] += 0.1f * bfhi(uh[j].x);
                sp[j][2] += 0.1f * bflo(uh[j].y);
                sp[j][3] += 0.1f * bfhi(uh[j].y);
            }
        }
        finish(sp);
    }

    // ---- passes 2,3: delta = uhat.v, b update, softmax, s-accumulate ----
#pragma unroll 1
    for (int pass = 0; pass < 2; pass++) {
        bool first = (pass == 0);    // pass2: b_prev = 0, write b_sh; pass3: read b_sh
        float sp[10][4];
#pragma unroll
        for (int j = 0; j < 10; j++)
#pragma unroll
            for (int k = 0; k < 4; k++) sp[j][k] = 0.f;
#pragma unroll 2
        for (int r = 0; r < 18; r++) {
            int i = r * 64 + w * 16 + ig;
            const unsigned short* up = ub + (size_t)i * 16 + qh * 4;
            uint2 uh[10];
#pragma unroll
            for (int j = 0; j < 10; j++) uh[j] = *(const uint2*)(up + (size_t)j * 18432);
            float d[10];
#pragma unroll
            for (int j = 0; j < 10; j++) {
                d[j] = bflo(uh[j].x) * v_ln[j][0] + bfhi(uh[j].x) * v_ln[j][1]
                     + bflo(uh[j].y) * v_ln[j][2] + bfhi(uh[j].y) * v_ln[j][3];
            }
#pragma unroll
            for (int j = 0; j < 10; j++) {
                d[j] += __shfl_xor(d[j], 1);
                d[j] += __shfl_xor(d[j], 2);
            }
            float bn[10];
            if (first) {
#pragma unroll
                for (int j = 0; j < 10; j++) bn[j] = d[j];
#pragma unroll
                for (int j = 0; j < 10; j++)
                    if (qh == (j & 3)) b_sh[i * 10 + j] = bn[j];
            } else {
#pragma unroll
                for (int j = 0; j < 10; j++) bn[j] = b_sh[i * 10 + j] + d[j];
            }
            float m = bn[0];
#pragma unroll
            for (int j = 1; j < 10; j++) m = fmaxf(m, bn[j]);
            float e[10], sum = 0.f;
#pragma unroll
            for (int j = 0; j < 10; j++) { e[j] = __expf(bn[j] - m); sum += e[j]; }
            float inv = 1.f / sum;
#pragma unroll
            for (int j = 0; j < 10; j++) {
                float c = e[j] * inv;
                sp[j][0] += c * bflo(uh[j].x);
                sp[j][1] += c * bfhi(uh[j].x);
                sp[j][2] += c * bflo(uh[j].y);
                sp[j][3] += c * bfhi(uh[j].y);
            }
        }
        finish(sp);
    }

    if (tid < 160) out[b * 160 + tid] = v_sh[tid];
}

extern "C" void kernel_launch(void* const* d_in, const int* in_sizes, int n_in,
                              void* d_out, int out_size, void* d_ws, size_t ws_size,
                              hipStream_t stream) {
    const float* input = (const float*)d_in[0];
    const float* c1w = (const float*)d_in[1];
    const float* c1b = (const float*)d_in[2];
    const float* c2w = (const float*)d_in[3];
    const float* c2b = (const float*)d_in[4];
    const float* capW = (const float*)d_in[5];
    float* out = (float*)d_out;

    // ws layout (bytes):
    //   [0)            u fp32 [512][9216] (conv2 slice 0 + bias)  18,874,368
    //   [+18874368)    part1 fp32                                 18,874,368
    //   [+37748736)    Wb bf16 [1152][1280]                        2,949,120
    //   [+43122688)    region B: Wt2 (11.0 MB) + h1n (104.9 MB) + part2,3 (37.7 MB)
    //                  uhat chunk (256 x 360 KB = 92.2 MB) reuses [B_OFF, B_OFF+115.9MB)
    //                  = the DEAD Wt2+h1n region only; part2,3 stay live for uhat reads.
    const size_t U_OFF = 0;
    const size_t P1_OFF = 18874368;
    const size_t WB_OFF = 37748736;
    const size_t B_OFF = 43122688;
    const size_t WT2_BYTES = (size_t)84 * 65536 * 2;       // 11,010,048
    const size_t H1N_BYTES = 104857600;
    const size_t PART_BYTES = (size_t)PART_FLOATS * 4;     // 18,874,368
    const size_t CONV_BYTES = WT2_BYTES + H1N_BYTES + 2 * PART_BYTES;  // 153.6 MB
    if (ws_size < B_OFF + CONV_BYTES) return;

    char* wsb = (char*)d_ws;
    float* u_buf = (float*)(wsb + U_OFF);
    float* part1 = (float*)(wsb + P1_OFF);
    unsigned short* Wb = (unsigned short*)(wsb + WB_OFF);
    unsigned short* Wt2 = (unsigned short*)(wsb + B_OFF);
    unsigned short* h1n = (unsigned short*)(wsb + B_OFF + WT2_BYTES);
    float* part23 = (float*)(wsb + B_OFF + WT2_BYTES + H1N_BYTES);
    unsigned short* uhatb = (unsigned short*)(wsb + B_OFF);   // aliases dead Wt2+h1n

    wcap_k<<<1440, 256, 0, stream>>>(capW, Wb);
    wt2_k<<<256, 256, 0, stream>>>(c2w, Wt2);
    conv1_k<<<512 * 16, 320, 0, stream>>>(input, c1w, c1b, h1n);
    conv2_k<<<dim3(144, 2, 4), 256, 0, stream>>>(h1n, Wt2, c2b, u_buf, part1, part23);

    const int Cr = 256;   // 256 x 360 KB = 92.2 MB <= 115.9 MB dead region
    for (int b0 = 0; b0 < 512; b0 += Cr) {
        uhat_k<<<dim3(18, Cr / 8), 256, 0, stream>>>(
            u_buf + (size_t)b0 * 9216, part1 + (size_t)b0 * 9216,
            part23 + (size_t)b0 * 9216, Wb, uhatb);
        route_k<<<Cr, 256, 0, stream>>>(uhatb, out + (size_t)b0 * 160);
    }
}

// Round 17
// 671.914 us; speedup vs baseline: 1.3056x; 1.0306x over previous
//
#include <hip/hip_runtime.h>
#include <hip/hip_bf16.h>

typedef __attribute__((ext_vector_type(8))) short bf16x8;
typedef __attribute__((ext_vector_type(4))) float f32x4;

static __device__ __forceinline__ unsigned short f2bf(float x) {
    __hip_bfloat16 h = __float2bfloat16(x);
    return *(unsigned short*)&h;
}
static __device__ __forceinline__ float bflo(unsigned int w) { return __uint_as_float(w << 16); }
static __device__ __forceinline__ float bfhi(unsigned int w) { return __uint_as_float(w & 0xffff0000u); }
static __device__ __forceinline__ float bf1(unsigned short u) { return __uint_as_float(((unsigned int)u) << 16); }

// async global->LDS DMA, 16B per lane, dest = wave-uniform base + lane*16
typedef __attribute__((address_space(1))) const void gvoid;
typedef __attribute__((address_space(3))) void lvoid;
static __device__ __forceinline__ void gl_lds16(const void* g, void* l) {
    __builtin_amdgcn_global_load_lds((gvoid*)g, (lvoid*)l, 16, 0, 0);
}

#define PART_FLOATS 4718592   // 512*9216

// ---------------- conv1 + ReLU: [512,1,28,28] -> h1n NHWC bf16 [512,20,20,256] ----------
// R13-verified fp32 structure (wr[81] register cache). Alternatives falsified:
// R24 MFMA port (307us); R25 LDS-weights (+18us).
__global__ __launch_bounds__(320) void conv1_k(const float* __restrict__ in,
                                               const float* __restrict__ w,
                                               const float* __restrict__ bias,
                                               unsigned short* __restrict__ h1n) {
    int blk = blockIdx.x;
    int b = blk >> 4;
    int c0 = (blk & 15) * 16;
    __shared__ float img[784];
    __shared__ float wl[16 * 81];
    __shared__ float bl[16];
    __shared__ unsigned short tr[20 * 328];
    int tid = threadIdx.x;
    for (int t = tid; t < 784; t += 320) img[t] = in[b * 784 + t];
    for (int t = tid; t < 1296; t += 320) wl[t] = w[c0 * 81 + t];
    if (tid < 16) bl[tid] = bias[c0 + tid];
    __syncthreads();

    int co = tid / 20, oy = tid % 20;
    float wr[81];
#pragma unroll
    for (int k = 0; k < 81; k++) wr[k] = wl[co * 81 + k];
    float acc[20];
    float bv = bl[co];
#pragma unroll
    for (int ox = 0; ox < 20; ox++) acc[ox] = bv;

#pragma unroll
    for (int ky = 0; ky < 9; ky++) {
        const float* rp = &img[(oy + ky) * 28];
        float r[28];
#pragma unroll
        for (int v = 0; v < 7; v++) {
            float4 t4 = ((const float4*)rp)[v];
            r[v * 4 + 0] = t4.x; r[v * 4 + 1] = t4.y;
            r[v * 4 + 2] = t4.z; r[v * 4 + 3] = t4.w;
        }
#pragma unroll
        for (int kx = 0; kx < 9; kx++) {
            float wv = wr[ky * 9 + kx];
#pragma unroll
            for (int ox = 0; ox < 20; ox++) acc[ox] += r[ox + kx] * wv;
        }
    }
#pragma unroll
    for (int ox = 0; ox < 20; ox++)
        tr[oy * 328 + ox * 16 + co] = f2bf(fmaxf(acc[ox], 0.f));
    __syncthreads();
    for (int g = tid; g < 800; g += 320) {
        int p = g >> 1, half = g & 1;
        uint4 v = *(uint4*)&tr[(p / 20) * 328 + (p % 20) * 16 + half * 8];
        *(uint4*)&h1n[(b * 400 + p) * 256 + c0 + half * 8] = v;
    }
}

// ---------------- merged preprocessing: wt2 (blocks 0-255) + wcap (blocks 256-1695) ------
// R26: one launch instead of two (saves one full dispatch+drain on the serial stream).
// wt2 part = R23 (coalesced float4 pass -> bf16 LDS [cin][84] -> vectorized plane
// writes); wcap part = f32->bf16 pack, same flat layout.
__global__ __launch_bounds__(256) void pre_k(const float* __restrict__ w2,
                                             unsigned short* __restrict__ Wt2,
                                             const float* __restrict__ W,
                                             unsigned short* __restrict__ Wb) {
    __shared__ unsigned short lw[256 * 84];   // used by wt2 blocks only
    int tid = threadIdx.x;
    if (blockIdx.x >= 256) {
        int idx4 = (blockIdx.x - 256) * 256 + tid;   // 368,640 total
        float4 v = *(const float4*)&W[(size_t)idx4 * 4];
        unsigned int lo = (unsigned int)f2bf(v.x) | ((unsigned int)f2bf(v.y) << 16);
        unsigned int hi = (unsigned int)f2bf(v.z) | ((unsigned int)f2bf(v.w) << 16);
        uint2 pk; pk.x = lo; pk.y = hi;
        *(uint2*)&Wb[(size_t)idx4 * 4] = pk;
        return;
    }
    int cout = blockIdx.x;
    lw[tid * 84 + 81] = 0; lw[tid * 84 + 82] = 0; lw[tid * 84 + 83] = 0;
    const float4* src = (const float4*)(w2 + (size_t)cout * 20736);
    for (int t = tid; t < 5184; t += 256) {
        float4 v = src[t];
        int flat = t * 4;
#pragma unroll
        for (int e = 0; e < 4; e++) {
            int f = flat + e;
            int cin = f / 81, kk = f - cin * 81;
            float x = (e == 0) ? v.x : (e == 1) ? v.y : (e == 2) ? v.z : v.w;
            lw[cin * 84 + kk] = f2bf(x);
        }
    }
    __syncthreads();
    int kko = tid >> 7, c2 = (tid & 127) * 2;
    for (int base = 0; base < 84; base += 2) {
        int kk = base + kko;
        unsigned int val = (unsigned int)lw[c2 * 84 + kk]
                         | ((unsigned int)lw[(c2 + 1) * 84 + kk] << 16);
        *(unsigned int*)&Wt2[(size_t)kk * 65536 + cout * 256 + c2] = val;
    }
}

// ---------------- conv2 implicit GEMM, bf16 MFMA, 128x128, split-K 4 ---------------------
// R12 (verified best, ~278-294us, SESSION CEILING for this structure): 2-phase double-
// buffered global_load_lds prefetch; one barrier per round; XOR swizzle via pre-swizzled
// SOURCE (rule 21). 64 KB LDS -> 2 blocks/CU.
// Failed alternatives: R16 direct-B regs (540us); R17 BK=32 (294); R18 counted-vmcnt on
// 2-phase (333); R21 XCD decode (299, FETCH 2.4x -> latency-bound proof); R22 BN=256
// 3-ring (360, 1 blk/CU killed TLP).
__global__ __launch_bounds__(256) void conv2_k(const unsigned short* __restrict__ h1n,
                                               const unsigned short* __restrict__ Wt2,
                                               const float* __restrict__ bias,
                                               float* __restrict__ u,
                                               float* __restrict__ part1,
                                               float* __restrict__ part23) {
    __shared__ unsigned short sA[2][128 * 64];   // 32 KB, XOR-swizzled, double-buffered
    __shared__ unsigned short sB[2][128 * 64];   // 32 KB, XOR-swizzled, double-buffered
    int tid = threadIdx.x;
    int m0 = blockIdx.x * 128;
    int n0 = blockIdx.y * 128;
    int slice = blockIdx.z;
    int ks = slice * 21;

    int wv = tid >> 6, lane = tid & 63;
    int wm = wv >> 1, wn = wv & 1;
    int lr = lane & 15, quad = lane >> 4;

    // staging geometry (per wave): 4 instrs for A + 4 for B, 8 rows per instr
    int lrow = lane >> 3, lslot = lane & 7;
    int kcoff = (lslot ^ lrow) * 8;           // pre-swizzled chunk offset (shorts)
    int aG[4], bG[4];
#pragma unroll
    for (int t = 0; t < 4; t++) {
        int r = wv * 32 + t * 8 + lrow;       // sA/sB row this lane feeds in instr t
        int R = m0 + r;
        int b = R / 36, m = R % 36;
        int oy = m / 6, ox = m % 6;
        aG[t] = b * 102400 + oy * 10240 + ox * 512 + kcoff;
        bG[t] = (n0 + r) * 256 + kcoff;
    }

    f32x4 acc[4][4];
#pragma unroll
    for (int i = 0; i < 4; i++)
#pragma unroll
        for (int j = 0; j < 4; j++) acc[i][j] = (f32x4){0.f, 0.f, 0.f, 0.f};

    auto stage = [&](int buf, int rr) {
        int kk = ks + (rr >> 2), cr = rr & 3;      // wave-uniform -> SALU
        int ky = kk / 9, kx = kk % 9;
        int aoff = ky * 5120 + kx * 256 + cr * 64;
        int boff = kk * 65536 + cr * 64;
        unsigned short* dA = &sA[buf][wv * 2048];
        unsigned short* dB = &sB[buf][wv * 2048];
#pragma unroll
        for (int t = 0; t < 4; t++)
            gl_lds16(h1n + aG[t] + aoff, dA + t * 512);
#pragma unroll
        for (int t = 0; t < 4; t++)
            gl_lds16(Wt2 + bG[t] + boff, dB + t * 512);
    };

    // prologue: fill buf0, drain, barrier
    stage(0, 0);
    __syncthreads();

    int cur = 0;
#pragma unroll 1
    for (int rr = 0; rr < 84; rr++) {
        if (rr < 83) stage(cur ^ 1, rr + 1);   // prefetch next round (stays in flight)
        const unsigned short* pA = &sA[cur][0];
        const unsigned short* pB = &sB[cur][0];
#pragma unroll
        for (int s = 0; s < 2; s++) {
            bf16x8 af[4], bf[4];
#pragma unroll
            for (int i = 0; i < 4; i++) {
                int arow = wm * 64 + i * 16 + lr;
                af[i] = *(bf16x8*)&pA[arow * 64 + 8 * ((s * 4 + quad) ^ (lr & 7))];
            }
#pragma unroll
            for (int j = 0; j < 4; j++) {
                int brow = wn * 64 + j * 16 + lr;
                bf[j] = *(bf16x8*)&pB[brow * 64 + 8 * ((s * 4 + quad) ^ (lr & 7))];
            }
#pragma unroll
            for (int i = 0; i < 4; i++)
#pragma unroll
                for (int j = 0; j < 4; j++)
                    acc[i][j] = __builtin_amdgcn_mfma_f32_16x16x32_bf16(
                        af[i], bf[j], acc[i][j], 0, 0, 0);
        }
        __syncthreads();   // drains prefetch vmcnt(0); it had the whole compute to land
        cur ^= 1;
    }

    // epilogue: C/D layout col=lane&15, row=quad*4+reg
    float* dst = (slice == 0) ? u : ((slice == 1) ? part1 : part23 + (size_t)(slice - 2) * PART_FLOATS);
#pragma unroll
    for (int j = 0; j < 4; j++) {
        int col = n0 + wn * 64 + j * 16 + lr;
        float bv = (slice == 0) ? bias[col] : 0.f;
#pragma unroll
        for (int i = 0; i < 4; i++) {
#pragma unroll
            for (int rg = 0; rg < 4; rg++) {
                int RR = m0 + wm * 64 + i * 16 + quad * 4 + rg;
                int bb = RR / 36, mm = RR % 36;
                int oyy = mm / 6, oxx = mm % 6;
                dst[bb * 9216 + oxx * 1536 + oyy * 256 + col] = acc[i][j][rg] + bv;
            }
        }
    }
}

// ---------------- u_hat: (u+p1+p2+p3)[b,i,p] x Wb[i,j,p,q] -> uhat bf16 [b][j][i*16+q] --
// R20 (verified): add-fold (190 MB add pass gone) + bf16 W (wl 16.6 KB) + 8 samples/
// block + float4 x 4-stream staging. LDS 18.4+16.6 = 35 KB -> 4 blocks/CU.
__global__ __launch_bounds__(256) void uhat_k(const float* __restrict__ u,
                                              const float* __restrict__ p1,
                                              const float* __restrict__ p23,
                                              const unsigned short* __restrict__ Wb,
                                              unsigned short* __restrict__ uhat) {
    int i0 = blockIdx.x * 64;
    int b0 = blockIdx.y * 8;      // LOCAL sample index within this chunk
    __shared__ float ul[8 * 576];           // [bb][il*9+p], 18.4 KB
    __shared__ unsigned short wl[64 * 130]; // 16.6 KB
    int tid = threadIdx.x;

    // fold-staging: 1024 float4-groups (8 bb x 128), 4 iterations/thread
    for (int t = tid; t < 1024; t += 256) {
        int bb = t >> 7, rq = t & 127;
        int r = rq * 4;
        size_t gidx = (size_t)(b0 + bb) * 9216 + i0 * 8 + r;
        float4 a = *(const float4*)&u[gidx];
        float4 x = *(const float4*)&p1[gidx];
        float4 y = *(const float4*)&p23[gidx];
        float4 z = *(const float4*)&p23[PART_FLOATS + gidx];
        float* d = &ul[bb * 576 + (r >> 3) * 9 + (r & 7)];
        d[0] = a.x + x.x + y.x + z.x;
        d[1] = a.y + x.y + y.y + z.y;
        d[2] = a.z + x.z + y.z + z.z;
        d[3] = a.w + x.w + y.w + z.w;
    }

    int il = tid & 63, g = tid >> 6;
    for (int j = 0; j < 10; j++) {
        __syncthreads();
        for (int t = tid; t < 4096; t += 256) {
            int li = t >> 6, cp = t & 63;   // 64 uint (2 bf16) per 128-col row
            *(unsigned int*)&wl[li * 130 + cp * 2] =
                *(const unsigned int*)&Wb[(size_t)(i0 + li) * 1280 + j * 128 + cp * 2];
        }
        __syncthreads();
#pragma unroll 1
        for (int bb = 0; bb < 8; bb++) {
            float ur[8];
#pragma unroll
            for (int p = 0; p < 8; p++) ur[p] = ul[bb * 576 + il * 9 + p];
            float a[4];
#pragma unroll
            for (int k = 0; k < 4; k++) {
                int q = g * 4 + k;
                float s = 0.f;
#pragma unroll
                for (int p = 0; p < 8; p++) s += ur[p] * bf1(wl[il * 130 + p * 16 + q]);
                a[k] = s;
            }
            unsigned int lo = (unsigned int)f2bf(a[0]) | ((unsigned int)f2bf(a[1]) << 16);
            unsigned int hi = (unsigned int)f2bf(a[2]) | ((unsigned int)f2bf(a[3]) << 16);
            uint2 pk; pk.x = lo; pk.y = hi;
            *(uint2*)&uhat[((size_t)(b0 + bb) * 10 + j) * 18432 + (size_t)(i0 + il) * 16 + g * 4] = pk;
        }
    }
}

// ---------------- fused dynamic routing: one block per batch sample ----------------------
// R13 (verified) + R26: 512 threads / 8 waves (was 256/4). route ran at 1 block/CU with
// 4 waves = 12.5% occupancy, latency-heavy (L2 uhat reads + serial softmax chains);
// 8 waves halves per-wave serial work (r<9, i = r*128 + w*16 + ig) and doubles
// latency-hiding. s_red grown to [8][160]; each i still covered exactly once.
__global__ __launch_bounds__(512) void route_k(const unsigned short* __restrict__ uhat,
                                               float* __restrict__ out) {
    int b = blockIdx.x;
    int tid = threadIdx.x;
    int w = tid >> 6, lane = tid & 63;
    int ig = lane >> 2, qh = lane & 3;
    __shared__ float b_sh[1152 * 10];   // 46 KB
    __shared__ float s_red[8 * 160];    // 5 KB
    __shared__ float v_sh[160];
    __shared__ float sc_sh[10];
    const unsigned short* ub = uhat + (size_t)b * 184320;

    float v_ln[10][4];   // this lane's v[j*16 + qh*4 + k]

    // reduce sp -> s -> squash -> v_sh -> v_ln  (shared tail for every pass)
    auto finish = [&](float sp[10][4]) {
#pragma unroll
        for (int j = 0; j < 10; j++)
#pragma unroll
            for (int k = 0; k < 4; k++) {
                float t = sp[j][k];
                t += __shfl_xor(t, 4);
                t += __shfl_xor(t, 8);
                t += __shfl_xor(t, 16);
                t += __shfl_xor(t, 32);
                sp[j][k] = t;
            }
        if (ig == 0) {   // lanes 0..3 of each wave hold the wave totals
#pragma unroll
            for (int j = 0; j < 10; j++) {
                f32x4 v4 = {sp[j][0], sp[j][1], sp[j][2], sp[j][3]};
                *(f32x4*)&s_red[w * 160 + j * 16 + qh * 4] = v4;
            }
        }
        __syncthreads();
        if (tid < 160) {
            float s = 0.f;
#pragma unroll
            for (int k = 0; k < 8; k++) s += s_red[k * 160 + tid];
            s_red[tid] = s;
        }
        __syncthreads();
        if (tid < 10) {
            float sq = 0.f;
#pragma unroll
            for (int q = 0; q < 16; q++) { float x = s_red[tid * 16 + q]; sq += x * x; }
            float norm = sqrtf(sq + 1e-8f);
            sc_sh[tid] = (sq / (1.0f + sq)) / norm;
        }
        __syncthreads();
        if (tid < 160) v_sh[tid] = s_red[tid] * sc_sh[tid >> 4];
        __syncthreads();
#pragma unroll
        for (int j = 0; j < 10; j++) {
            f32x4 v4 = *(const f32x4*)&v_sh[j * 16 + qh * 4];
            v_ln[j][0] = v4[0]; v_ln[j][1] = v4[1]; v_ln[j][2] = v4[2]; v_ln[j][3] = v4[3];
        }
        __syncthreads();
    };

    // ---- pass 1: c = 0.1 uniform ----
    {
        float sp[10][4];
#pragma unroll
        for (int j = 0; j < 10; j++)
#pragma unroll
            for (int k = 0; k < 4; k++) sp[j][k] = 0.f;
#pragma unroll 1
        for (int r = 0; r < 9; r++) {
            int i = r * 128 + w * 16 + ig;
            const unsigned short* up = ub + (size_t)i * 16 + qh * 4;
            uint2 uh[10];
#pragma unroll
            for (int j = 0; j < 10; j++) uh[j] = *(const uint2*)(up + (size_t)j * 18432);
#pragma unroll
            for (int j = 0; j < 10; j++) {
                sp[j][0] += 0.1f * bflo(uh[j].x);
                sp[j][1] += 0.1f * bfhi(uh[j].x);
                sp[j][2] += 0.1f * bflo(uh[j].y);
                sp[j][3] += 0.1f * bfhi(uh[j].y);
            }
        }
        finish(sp);
    }

    // ---- passes 2,3: delta = uhat.v, b update, softmax, s-accumulate ----
#pragma unroll 1
    for (int pass = 0; pass < 2; pass++) {
        bool first = (pass == 0);    // pass2: b_prev = 0, write b_sh; pass3: read b_sh
        float sp[10][4];
#pragma unroll
        for (int j = 0; j < 10; j++)
#pragma unroll
            for (int k = 0; k < 4; k++) sp[j][k] = 0.f;
#pragma unroll 1
        for (int r = 0; r < 9; r++) {
            int i = r * 128 + w * 16 + ig;
            const unsigned short* up = ub + (size_t)i * 16 + qh * 4;
            uint2 uh[10];
#pragma unroll
            for (int j = 0; j < 10; j++) uh[j] = *(const uint2*)(up + (size_t)j * 18432);
            float d[10];
#pragma unroll
            for (int j = 0; j < 10; j++) {
                d[j] = bflo(uh[j].x) * v_ln[j][0] + bfhi(uh[j].x) * v_ln[j][1]
                     + bflo(uh[j].y) * v_ln[j][2] + bfhi(uh[j].y) * v_ln[j][3];
            }
#pragma unroll
            for (int j = 0; j < 10; j++) {
                d[j] += __shfl_xor(d[j], 1);
                d[j] += __shfl_xor(d[j], 2);
            }
            float bn[10];
            if (first) {
#pragma unroll
                for (int j = 0; j < 10; j++) bn[j] = d[j];
#pragma unroll
                for (int j = 0; j < 10; j++)
                    if (qh == (j & 3)) b_sh[i * 10 + j] = bn[j];
            } else {
#pragma unroll
                for (int j = 0; j < 10; j++) bn[j] = b_sh[i * 10 + j] + d[j];
            }
            float m = bn[0];
#pragma unroll
            for (int j = 1; j < 10; j++) m = fmaxf(m, bn[j]);
            float e[10], sum = 0.f;
#pragma unroll
            for (int j = 0; j < 10; j++) { e[j] = __expf(bn[j] - m); sum += e[j]; }
            float inv = 1.f / sum;
#pragma unroll
            for (int j = 0; j < 10; j++) {
                float c = e[j] * inv;
                sp[j][0] += c * bflo(uh[j].x);
                sp[j][1] += c * bfhi(uh[j].x);
                sp[j][2] += c * bflo(uh[j].y);
                sp[j][3] += c * bfhi(uh[j].y);
            }
        }
        finish(sp);
    }

    if (tid < 160) out[b * 160 + tid] = v_sh[tid];
}

extern "C" void kernel_launch(void* const* d_in, const int* in_sizes, int n_in,
                              void* d_out, int out_size, void* d_ws, size_t ws_size,
                              hipStream_t stream) {
    const float* input = (const float*)d_in[0];
    const float* c1w = (const float*)d_in[1];
    const float* c1b = (const float*)d_in[2];
    const float* c2w = (const float*)d_in[3];
    const float* c2b = (const float*)d_in[4];
    const float* capW = (const float*)d_in[5];
    float* out = (float*)d_out;

    // ws layout (bytes):
    //   [0)            u fp32 [512][9216] (conv2 slice 0 + bias)  18,874,368
    //   [+18874368)    part1 fp32                                 18,874,368
    //   [+37748736)    Wb bf16 [1152][1280]                        2,949,120
    //   [+43122688)    region B: Wt2 (11.0 MB) + h1n (104.9 MB) + part2,3 (37.7 MB)
    //                  uhat chunk (256 x 360 KB = 92.2 MB) reuses [B_OFF, B_OFF+115.9MB)
    //                  = the DEAD Wt2+h1n region only; part2,3 stay live for uhat reads.
    const size_t U_OFF = 0;
    const size_t P1_OFF = 18874368;
    const size_t WB_OFF = 37748736;
    const size_t B_OFF = 43122688;
    const size_t WT2_BYTES = (size_t)84 * 65536 * 2;       // 11,010,048
    const size_t H1N_BYTES = 104857600;
    const size_t PART_BYTES = (size_t)PART_FLOATS * 4;     // 18,874,368
    const size_t CONV_BYTES = WT2_BYTES + H1N_BYTES + 2 * PART_BYTES;  // 153.6 MB
    if (ws_size < B_OFF + CONV_BYTES) return;

    char* wsb = (char*)d_ws;
    float* u_buf = (float*)(wsb + U_OFF);
    float* part1 = (float*)(wsb + P1_OFF);
    unsigned short* Wb = (unsigned short*)(wsb + WB_OFF);
    unsigned short* Wt2 = (unsigned short*)(wsb + B_OFF);
    unsigned short* h1n = (unsigned short*)(wsb + B_OFF + WT2_BYTES);
    float* part23 = (float*)(wsb + B_OFF + WT2_BYTES + H1N_BYTES);
    unsigned short* uhatb = (unsigned short*)(wsb + B_OFF);   // aliases dead Wt2+h1n

    pre_k<<<1696, 256, 0, stream>>>(c2w, Wt2, capW, Wb);
    conv1_k<<<512 * 16, 320, 0, stream>>>(input, c1w, c1b, h1n);
    conv2_k<<<dim3(144, 2, 4), 256, 0, stream>>>(h1n, Wt2, c2b, u_buf, part1, part23);

    const int Cr = 256;   // 256 x 360 KB = 92.2 MB <= 115.9 MB dead region
    for (int b0 = 0; b0 < 512; b0 += Cr) {
        uhat_k<<<dim3(18, Cr / 8), 256, 0, stream>>>(
            u_buf + (size_t)b0 * 9216, part1 + (size_t)b0 * 9216,
            part23 + (size_t)b0 * 9216, Wb, uhatb);
        route_k<<<Cr, 512, 0, stream>>>(uhatb, out + (size_t)b0 * 160);
    }
}